// Round 1
// baseline (227.531 us; speedup 1.0000x reference)
//
#include <hip/hip_runtime.h>

// IDWT reconstruction layer.
// x: (B=16, L=32768, 64) f32, channels [0,32)=approx, [32,64)=detail.
// out: (16, 2L=65536, 32) f32.
//
// out[b, 2p,   c] = sum_t lo[2t+1]*A[p-1+t] + hi[2t+1]*D[p-1+t]
// out[b, 2p+1, c] = sum_t lo[2t  ]*A[p-1+t] + hi[2t  ]*D[p-1+t]
// (t in 0..3; rows outside [0,L) contribute zero)

#define B_    16
#define L_    32768
#define CIN_  64
#define COUT_ 32

__global__ __launch_bounds__(256) void idwt_kernel(
    const float* __restrict__ x,
    const float* __restrict__ rec_lo,
    const float* __restrict__ rec_hi,
    float* __restrict__ out)
{
    const int tid = blockIdx.x * blockDim.x + threadIdx.x;
    const int g  = tid & 7;          // channel group of 4 (c = 4g)
    const int pp = tid >> 3;         // (b, p) combined
    const int p  = pp & (L_ - 1);
    const int b  = pp >> 15;         // L_ = 2^15

    // base pointer for this batch + channel group
    const float* xb = x + b * (L_ * CIN_) + (g << 2);

    float A[4][4];
    float D[4][4];
#pragma unroll
    for (int t = 0; t < 4; ++t) {
        const int j = p - 1 + t;
        if (j >= 0 && j < L_) {
            const float4 a = *(const float4*)(xb + j * CIN_);
            const float4 d = *(const float4*)(xb + j * CIN_ + COUT_);
            A[t][0] = a.x; A[t][1] = a.y; A[t][2] = a.z; A[t][3] = a.w;
            D[t][0] = d.x; D[t][1] = d.y; D[t][2] = d.z; D[t][3] = d.w;
        } else {
#pragma unroll
            for (int c = 0; c < 4; ++c) { A[t][c] = 0.f; D[t][c] = 0.f; }
        }
    }

    // wave-uniform filter loads (compiler scalarizes to s_load)
    float lo[8], hi[8];
#pragma unroll
    for (int k = 0; k < 8; ++k) { lo[k] = rec_lo[k]; hi[k] = rec_hi[k]; }

    float ev[4], od[4];
#pragma unroll
    for (int c = 0; c < 4; ++c) {
        float e = 0.f, o = 0.f;
#pragma unroll
        for (int t = 0; t < 4; ++t) {
            e = fmaf(lo[2 * t + 1], A[t][c], e);
            e = fmaf(hi[2 * t + 1], D[t][c], e);
            o = fmaf(lo[2 * t],     A[t][c], o);
            o = fmaf(hi[2 * t],     D[t][c], o);
        }
        ev[c] = e; od[c] = o;
    }

    float* orow = out + (b * (2 * L_) + 2 * p) * COUT_ + (g << 2);
    *(float4*)(orow)         = make_float4(ev[0], ev[1], ev[2], ev[3]);
    *(float4*)(orow + COUT_) = make_float4(od[0], od[1], od[2], od[3]);
}

extern "C" void kernel_launch(void* const* d_in, const int* in_sizes, int n_in,
                              void* d_out, int out_size, void* d_ws, size_t ws_size,
                              hipStream_t stream) {
    const float* x      = (const float*)d_in[0];
    const float* rec_lo = (const float*)d_in[1];
    const float* rec_hi = (const float*)d_in[2];
    float* out = (float*)d_out;

    const int total_threads = B_ * L_ * (COUT_ / 4);  // 16*32768*8 = 4,194,304
    const int block = 256;
    idwt_kernel<<<total_threads / block, block, 0, stream>>>(x, rec_lo, rec_hi, out);
}